// Round 2
// baseline (7527.235 us; speedup 1.0000x reference)
//
#include <hip/hip_runtime.h>
#include <math.h>

// Problem constants (fixed by reference setup_inputs)
#define NODES 16384   // bs*N
#define CIN   256     // C
#define HD    512     // H*D
#define NPOS  4096    // N
#define NHEAD 8       // H
#define DDIM  64      // D

// ---------------------------------------------------------------------------
// GEMM: O[r,c] = sum_k A[r,k] * W[c,k]   (A: NODES x CIN, W: HD x CIN)
// blockIdx.z selects {Wq->Q, Wk->K, Wv->V}. 64x64 tile, 256 threads, 4x4/thread.
// LDS tiles stored k-major (transposed) so inner loop uses ds_read_b128.
// ---------------------------------------------------------------------------
__global__ __launch_bounds__(256) void gemm_nt_kernel(
    const float* __restrict__ A,
    const float* __restrict__ Wq, const float* __restrict__ Wk,
    const float* __restrict__ Wv,
    float* __restrict__ Q, float* __restrict__ K, float* __restrict__ V) {
  const float* B;
  float* O;
  if (blockIdx.z == 0)      { B = Wq; O = Q; }
  else if (blockIdx.z == 1) { B = Wk; O = K; }
  else                      { B = Wv; O = V; }

  __shared__ float As[32][68];  // [kk][row], pad 68 keeps float4 16B-aligned
  __shared__ float Bs[32][68];

  const int tid = threadIdx.x;
  const int tx = tid & 15, ty = tid >> 4;
  const int row0 = blockIdx.y * 64, col0 = blockIdx.x * 64;

  float acc[4][4] = {};

  for (int kt = 0; kt < CIN; kt += 32) {
#pragma unroll
    for (int u = 0; u < 2; ++u) {
      int t = tid + u * 256;          // 512 float4 loads per tile pair
      int r = t >> 3, c4 = (t & 7) << 2;
      float4 av = *(const float4*)(A + (size_t)(row0 + r) * CIN + kt + c4);
      As[c4 + 0][r] = av.x; As[c4 + 1][r] = av.y;
      As[c4 + 2][r] = av.z; As[c4 + 3][r] = av.w;
      float4 bv = *(const float4*)(B + (size_t)(col0 + r) * CIN + kt + c4);
      Bs[c4 + 0][r] = bv.x; Bs[c4 + 1][r] = bv.y;
      Bs[c4 + 2][r] = bv.z; Bs[c4 + 3][r] = bv.w;
    }
    __syncthreads();
#pragma unroll
    for (int kk = 0; kk < 32; ++kk) {
      float4 a = *(const float4*)&As[kk][ty * 4];
      float4 b = *(const float4*)&Bs[kk][tx * 4];
      acc[0][0] += a.x * b.x; acc[0][1] += a.x * b.y;
      acc[0][2] += a.x * b.z; acc[0][3] += a.x * b.w;
      acc[1][0] += a.y * b.x; acc[1][1] += a.y * b.y;
      acc[1][2] += a.y * b.z; acc[1][3] += a.y * b.w;
      acc[2][0] += a.z * b.x; acc[2][1] += a.z * b.y;
      acc[2][2] += a.z * b.z; acc[2][3] += a.z * b.w;
      acc[3][0] += a.w * b.x; acc[3][1] += a.w * b.y;
      acc[3][2] += a.w * b.z; acc[3][3] += a.w * b.w;
    }
    __syncthreads();
  }
#pragma unroll
  for (int i = 0; i < 4; ++i) {
    float4 o = make_float4(acc[i][0], acc[i][1], acc[i][2], acc[i][3]);
    *(float4*)(O + (size_t)(row0 + ty * 4 + i) * HD + col0 + tx * 4) = o;
  }
}

// ---------------------------------------------------------------------------
// RoPE (in-place on Q and K). Flat idx f in the (bs,H,N,D) view:
// rem=(b*H+hd)*N+n selects the 64-dim slice; within it, halves q in {0,1}
// (x/y axis, 32 dims each); rotate pairs (i, i+16), i in [0,16).
// angle = pos[b,n,q]*64 * 10000^(-i/16).
// One thread per pair (race-free in-place).
// ---------------------------------------------------------------------------
__global__ __launch_bounds__(256) void rope_kernel(
    float* __restrict__ Q, float* __restrict__ K,
    const float* __restrict__ pos) {
  int t = blockIdx.x * 256 + threadIdx.x;    // [0, 2*2^22)
  float* M = (t >> 22) ? K : Q;
  int p = t & ((1 << 22) - 1);               // pair id within matrix
  int pid = p & 31;                          // (q,i)
  int rem = p >> 5;                          // (b*H+hd)*N + n, [0,131072)
  int n = rem & (NPOS - 1);
  int b = rem >> 15;                         // rem / (H*N)
  int q = pid >> 4, i = pid & 15;

  int base = rem * DDIM + q * 32 + i;
  float t0 = M[base];
  float t1 = M[base + 16];
  float ps = pos[((size_t)((b << 12) + n)) * 2 + q] * 64.0f;
  // inv_freq[i] = 10000^(-i/16) = exp2(-i * log2(10000)/16)
  float invf = exp2f(-(float)i * 0.83048202372184f);
  float ang = ps * invf;
  float s, c;
  sincosf(ang, &s, &c);
  M[base]      = t0 * c - t1 * s;
  M[base + 16] = t1 * c + t0 * s;
}

// ---------------------------------------------------------------------------
// Edge attention: one wave (64 lanes) per edge.
// lane = hh*8+g : head hh, dim-chunk g (8 floats). Dot over D=64 via 8-lane
// shfl_xor reduce. Scatter V[src]*score into wV[dst] with fp32 atomics.
// ---------------------------------------------------------------------------
__global__ __launch_bounds__(256) void edge_kernel(
    const float* __restrict__ Q, const float* __restrict__ K,
    const float* __restrict__ V,
    const int* __restrict__ src, const int* __restrict__ dst,
    float* __restrict__ wV, float* __restrict__ z, int E) {
  int wave = blockIdx.x * 4 + (threadIdx.x >> 6);
  if (wave >= E) return;
  int lane = threadIdx.x & 63;
  int s = src[wave];
  int d = dst[wave];
  int hh = lane >> 3, g = lane & 7;

  const float* kp = K + (size_t)s * HD + hh * DDIM + g * 8;
  const float* qp = Q + (size_t)d * HD + hh * DDIM + g * 8;
  float4 k0 = *(const float4*)kp;
  float4 k1 = *(const float4*)(kp + 4);
  float4 q0 = *(const float4*)qp;
  float4 q1 = *(const float4*)(qp + 4);
  float dot = k0.x * q0.x + k0.y * q0.y + k0.z * q0.z + k0.w * q0.w +
              k1.x * q1.x + k1.y * q1.y + k1.z * q1.z + k1.w * q1.w;
  dot += __shfl_xor(dot, 1);
  dot += __shfl_xor(dot, 2);
  dot += __shfl_xor(dot, 4);
  float sc = expf(fminf(fmaxf(dot * 0.125f, -5.0f), 5.0f));

  const float* vp = V + (size_t)s * HD + lane * 8;
  float* op = wV + (size_t)d * HD + lane * 8;
  float4 v0 = *(const float4*)vp;
  float4 v1 = *(const float4*)(vp + 4);
  unsafeAtomicAdd(op + 0, v0.x * sc);
  unsafeAtomicAdd(op + 1, v0.y * sc);
  unsafeAtomicAdd(op + 2, v0.z * sc);
  unsafeAtomicAdd(op + 3, v0.w * sc);
  unsafeAtomicAdd(op + 4, v1.x * sc);
  unsafeAtomicAdd(op + 5, v1.y * sc);
  unsafeAtomicAdd(op + 6, v1.z * sc);
  unsafeAtomicAdd(op + 7, v1.w * sc);
  if (g == 0) unsafeAtomicAdd(z + (size_t)d * NHEAD + hh, sc);
}

// ---------------------------------------------------------------------------
// out = wV / z  (in-place on d_out). float4 per thread; 4 elems never cross
// a head boundary (64 % 4 == 0).
// ---------------------------------------------------------------------------
__global__ __launch_bounds__(256) void div_kernel(
    float* __restrict__ out, const float* __restrict__ z) {
  int t = blockIdx.x * 256 + threadIdx.x;    // [0, NODES*HD/4)
  float4* o4 = (float4*)out;
  float4 v = o4[t];
  float inv = 1.0f / z[t >> 4];              // (t*4)/64
  v.x *= inv; v.y *= inv; v.z *= inv; v.w *= inv;
  o4[t] = v;
}

extern "C" void kernel_launch(void* const* d_in, const int* in_sizes, int n_in,
                              void* d_out, int out_size, void* d_ws,
                              size_t ws_size, hipStream_t stream) {
  const float* h   = (const float*)d_in[0];
  const float* pos = (const float*)d_in[1];
  const float* Wq  = (const float*)d_in[2];
  const float* Wk  = (const float*)d_in[3];
  const float* Wv  = (const float*)d_in[4];
  const int* src   = (const int*)d_in[5];
  const int* dst   = (const int*)d_in[6];
  const int E = in_sizes[5];

  float* Q = (float*)d_ws;                 // NODES*HD
  float* K = Q + (size_t)NODES * HD;
  float* V = K + (size_t)NODES * HD;
  float* z = V + (size_t)NODES * HD;       // NODES*NHEAD
  float* out = (float*)d_out;

  hipMemsetAsync(d_out, 0, (size_t)NODES * HD * sizeof(float), stream);
  hipMemsetAsync(z, 0, (size_t)NODES * NHEAD * sizeof(float), stream);

  gemm_nt_kernel<<<dim3(HD / 64, NODES / 64, 3), 256, 0, stream>>>(
      h, Wq, Wk, Wv, Q, K, V);

  // 2 matrices * NODES*HD/2 pairs = 2^23 threads
  rope_kernel<<<(2u << 22) / 256, 256, 0, stream>>>(Q, K, pos);

  edge_kernel<<<(E + 3) / 4, 256, 0, stream>>>(Q, K, V, src, dst, out, z, E);

  div_kernel<<<(NODES * HD / 4) / 256, 256, 0, stream>>>(out, z);
}

// Round 3
// 632.665 us; speedup vs baseline: 11.8977x; 11.8977x over previous
//
#include <hip/hip_runtime.h>
#include <math.h>

// Problem constants (fixed by reference setup_inputs)
#define NODES 16384   // bs*N
#define CIN   256     // C
#define HD    512     // H*D
#define NPOS  4096    // N
#define NHEAD 8       // H
#define DDIM  64      // D

// ---------------------------------------------------------------------------
// GEMM: O[r,c] = sum_k A[r,k] * W[c,k]   (A: NODES x CIN, W: HD x CIN)
// blockIdx.z selects {Wq->Q, Wk->K, Wv->V}. 64x64 tile, 256 threads, 4x4/thread.
// ---------------------------------------------------------------------------
__global__ __launch_bounds__(256) void gemm_nt_kernel(
    const float* __restrict__ A,
    const float* __restrict__ Wq, const float* __restrict__ Wk,
    const float* __restrict__ Wv,
    float* __restrict__ Q, float* __restrict__ K, float* __restrict__ V) {
  const float* B;
  float* O;
  if (blockIdx.z == 0)      { B = Wq; O = Q; }
  else if (blockIdx.z == 1) { B = Wk; O = K; }
  else                      { B = Wv; O = V; }

  __shared__ float As[32][68];  // [kk][row], pad 68 keeps float4 16B-aligned
  __shared__ float Bs[32][68];

  const int tid = threadIdx.x;
  const int tx = tid & 15, ty = tid >> 4;
  const int row0 = blockIdx.y * 64, col0 = blockIdx.x * 64;

  float acc[4][4] = {};

  for (int kt = 0; kt < CIN; kt += 32) {
#pragma unroll
    for (int u = 0; u < 2; ++u) {
      int t = tid + u * 256;          // 512 float4 loads per tile pair
      int r = t >> 3, c4 = (t & 7) << 2;
      float4 av = *(const float4*)(A + (size_t)(row0 + r) * CIN + kt + c4);
      As[c4 + 0][r] = av.x; As[c4 + 1][r] = av.y;
      As[c4 + 2][r] = av.z; As[c4 + 3][r] = av.w;
      float4 bv = *(const float4*)(B + (size_t)(col0 + r) * CIN + kt + c4);
      Bs[c4 + 0][r] = bv.x; Bs[c4 + 1][r] = bv.y;
      Bs[c4 + 2][r] = bv.z; Bs[c4 + 3][r] = bv.w;
    }
    __syncthreads();
#pragma unroll
    for (int kk = 0; kk < 32; ++kk) {
      float4 a = *(const float4*)&As[kk][ty * 4];
      float4 b = *(const float4*)&Bs[kk][tx * 4];
      acc[0][0] += a.x * b.x; acc[0][1] += a.x * b.y;
      acc[0][2] += a.x * b.z; acc[0][3] += a.x * b.w;
      acc[1][0] += a.y * b.x; acc[1][1] += a.y * b.y;
      acc[1][2] += a.y * b.z; acc[1][3] += a.y * b.w;
      acc[2][0] += a.z * b.x; acc[2][1] += a.z * b.y;
      acc[2][2] += a.z * b.z; acc[2][3] += a.z * b.w;
      acc[3][0] += a.w * b.x; acc[3][1] += a.w * b.y;
      acc[3][2] += a.w * b.z; acc[3][3] += a.w * b.w;
    }
    __syncthreads();
  }
#pragma unroll
  for (int i = 0; i < 4; ++i) {
    float4 o = make_float4(acc[i][0], acc[i][1], acc[i][2], acc[i][3]);
    *(float4*)(O + (size_t)(row0 + ty * 4 + i) * HD + col0 + tx * 4) = o;
  }
}

// ---------------------------------------------------------------------------
// RoPE (in-place on Q and K). See round-0 derivation; one thread per
// rotation pair (i, i+16) so in-place is race-free.
// ---------------------------------------------------------------------------
__global__ __launch_bounds__(256) void rope_kernel(
    float* __restrict__ Q, float* __restrict__ K,
    const float* __restrict__ pos) {
  int t = blockIdx.x * 256 + threadIdx.x;    // [0, 2*2^22)
  float* M = (t >> 22) ? K : Q;
  int p = t & ((1 << 22) - 1);               // pair id within matrix
  int pid = p & 31;                          // (q,i)
  int rem = p >> 5;                          // (b*H+hd)*N + n, [0,131072)
  int n = rem & (NPOS - 1);
  int b = rem >> 15;                         // rem / (H*N)
  int q = pid >> 4, i = pid & 15;

  int base = rem * DDIM + q * 32 + i;
  float t0 = M[base];
  float t1 = M[base + 16];
  float ps = pos[((size_t)((b << 12) + n)) * 2 + q] * 64.0f;
  float invf = exp2f(-(float)i * 0.83048202372184f);  // 10000^(-i/16)
  float ang = ps * invf;
  float s, c;
  sincosf(ang, &s, &c);
  M[base]      = t0 * c - t1 * s;
  M[base + 16] = t1 * c + t0 * s;
}

// ---------------------------------------------------------------------------
// Counting sort of edges by dst: histogram -> prefix scan -> scatter.
// ---------------------------------------------------------------------------
__global__ __launch_bounds__(256) void hist_kernel(
    const int* __restrict__ dst, int* __restrict__ count, int E) {
  int t = blockIdx.x * 256 + threadIdx.x;
  if (t < E) atomicAdd(&count[dst[t]], 1);
}

__global__ __launch_bounds__(256) void scan_kernel(
    const int* __restrict__ count, int* __restrict__ offset,
    int* __restrict__ cursor) {
  __shared__ int psum[256];
  __shared__ int pref[256];
  int t = threadIdx.x;
  int base = t * (NODES / 256);              // 64 counts per thread
  int s = 0;
  for (int i = 0; i < NODES / 256; ++i) s += count[base + i];
  psum[t] = s;
  __syncthreads();
  if (t == 0) {
    int run = 0;
    for (int i = 0; i < 256; ++i) { pref[i] = run; run += psum[i]; }
  }
  __syncthreads();
  int off = pref[t];
  for (int i = 0; i < NODES / 256; ++i) {
    int c = count[base + i];
    offset[base + i] = off;
    cursor[base + i] = off;
    off += c;
  }
  if (t == 255) offset[NODES] = off;
}

__global__ __launch_bounds__(256) void scatter_kernel(
    const int* __restrict__ src, const int* __restrict__ dst,
    int* __restrict__ cursor, int* __restrict__ srcs, int E) {
  int t = blockIdx.x * 256 + threadIdx.x;
  if (t < E) {
    int p = atomicAdd(&cursor[dst[t]], 1);
    srcs[p] = src[t];
  }
}

// ---------------------------------------------------------------------------
// Node-centric attention: one workgroup (4 waves) per destination node.
// Wave processes one edge at a time: lane = hh*8+g; dot via 8-lane shfl
// reduce; per-lane register accumulation of its 8 output dims; cross-wave
// reduce in LDS; divide by z; single final store. Zero global atomics.
// ---------------------------------------------------------------------------
__global__ __launch_bounds__(256) void node_kernel(
    const float* __restrict__ Q, const float* __restrict__ K,
    const float* __restrict__ V,
    const int* __restrict__ srcs, const int* __restrict__ offset,
    float* __restrict__ out) {
  __shared__ float wv[4][HD];
  __shared__ float zb[4][NHEAD];
  const int n = blockIdx.x;
  const int tid = threadIdx.x;
  const int lane = tid & 63, w = tid >> 6;
  const int hh = lane >> 3, g = lane & 7;

  const int beg = offset[n], end = offset[n + 1];

  const float4* qp = (const float4*)(Q + (size_t)n * HD + hh * DDIM + g * 8);
  const float4 q0 = qp[0], q1 = qp[1];

  float a0 = 0, a1 = 0, a2 = 0, a3 = 0, a4 = 0, a5 = 0, a6 = 0, a7 = 0;
  float zacc = 0.f;

  for (int i = beg + w; i < end; i += 4) {
    int s = srcs[i];
    const float4* kp = (const float4*)(K + (size_t)s * HD + hh * DDIM + g * 8);
    float4 k0 = kp[0], k1 = kp[1];
    float dot = k0.x * q0.x + k0.y * q0.y + k0.z * q0.z + k0.w * q0.w +
                k1.x * q1.x + k1.y * q1.y + k1.z * q1.z + k1.w * q1.w;
    dot += __shfl_xor(dot, 1);
    dot += __shfl_xor(dot, 2);
    dot += __shfl_xor(dot, 4);
    float sc = expf(fminf(fmaxf(dot * 0.125f, -5.0f), 5.0f));
    const float4* vp = (const float4*)(V + (size_t)s * HD + lane * 8);
    float4 v0 = vp[0], v1 = vp[1];
    a0 += v0.x * sc; a1 += v0.y * sc; a2 += v0.z * sc; a3 += v0.w * sc;
    a4 += v1.x * sc; a5 += v1.y * sc; a6 += v1.z * sc; a7 += v1.w * sc;
    zacc += sc;   // all 8 lanes of a head group hold the same sc
  }

  *(float4*)&wv[w][lane * 8]     = make_float4(a0, a1, a2, a3);
  *(float4*)&wv[w][lane * 8 + 4] = make_float4(a4, a5, a6, a7);
  if (g == 0) zb[w][hh] = zacc;
  __syncthreads();

  // 256 threads reduce 4 partial copies -> 512 dims (2 per thread)
  const int d0 = tid * 2;
  float r0 = wv[0][d0] + wv[1][d0] + wv[2][d0] + wv[3][d0];
  float r1 = wv[0][d0 + 1] + wv[1][d0 + 1] + wv[2][d0 + 1] + wv[3][d0 + 1];
  const int head = d0 >> 6;
  float zz = zb[0][head] + zb[1][head] + zb[2][head] + zb[3][head];
  float inv = 1.0f / zz;
  *(float2*)&out[(size_t)n * HD + d0] = make_float2(r0 * inv, r1 * inv);
}

extern "C" void kernel_launch(void* const* d_in, const int* in_sizes, int n_in,
                              void* d_out, int out_size, void* d_ws,
                              size_t ws_size, hipStream_t stream) {
  const float* h   = (const float*)d_in[0];
  const float* pos = (const float*)d_in[1];
  const float* Wq  = (const float*)d_in[2];
  const float* Wk  = (const float*)d_in[3];
  const float* Wv  = (const float*)d_in[4];
  const int* src   = (const int*)d_in[5];
  const int* dst   = (const int*)d_in[6];
  const int E = in_sizes[5];

  float* Q = (float*)d_ws;                 // NODES*HD
  float* K = Q + (size_t)NODES * HD;
  float* V = K + (size_t)NODES * HD;
  int* count  = (int*)(V + (size_t)NODES * HD);  // NODES
  int* offset = count + NODES;                   // NODES+1
  int* cursor = offset + NODES + 1;              // NODES
  int* srcs   = cursor + NODES;                  // E
  float* out = (float*)d_out;

  hipMemsetAsync(count, 0, NODES * sizeof(int), stream);

  gemm_nt_kernel<<<dim3(HD / 64, NODES / 64, 3), 256, 0, stream>>>(
      h, Wq, Wk, Wv, Q, K, V);

  rope_kernel<<<(2u << 22) / 256, 256, 0, stream>>>(Q, K, pos);

  hist_kernel<<<(E + 255) / 256, 256, 0, stream>>>(dst, count, E);
  scan_kernel<<<1, 256, 0, stream>>>(count, offset, cursor);
  scatter_kernel<<<(E + 255) / 256, 256, 0, stream>>>(src, dst, cursor, srcs, E);

  node_kernel<<<NODES, 256, 0, stream>>>(Q, K, V, srcs, offset, out);
}

// Round 6
// 322.010 us; speedup vs baseline: 23.3758x; 1.9647x over previous
//
#include <hip/hip_runtime.h>
#include <math.h>

// Problem constants (fixed by reference setup_inputs)
#define NODES 16384   // bs*N
#define CIN   256     // C (= GEMM K)
#define HD    512     // H*D (= GEMM N)
#define NPOS  4096    // N
#define NHEAD 8       // H
#define DDIM  64      // D
#define HN    (NODES * CIN)   // h elements = 4194304
#define WN    (HD * CIN)      // one W = 131072

typedef float f32x4 __attribute__((ext_vector_type(4)));
typedef unsigned int u32x4 __attribute__((ext_vector_type(4)));
typedef short s16x8 __attribute__((ext_vector_type(8)));   // 8 bf16 = 4 VGPRs

__device__ inline unsigned short f2bf(float f) {   // RNE f32 -> bf16 bits
  unsigned int u = __float_as_uint(f);
  u += 0x7fffu + ((u >> 16) & 1u);
  return (unsigned short)(u >> 16);
}

// ---------------------------------------------------------------------------
// Convert h, Wq, Wk, Wv (fp32) -> bf16, packed contiguously in ws.
// One thread per 8 elements.
// ---------------------------------------------------------------------------
__global__ __launch_bounds__(256) void conv_kernel(
    const float* __restrict__ h, const float* __restrict__ wq,
    const float* __restrict__ wk, const float* __restrict__ wv,
    unsigned short* __restrict__ out) {
  size_t e = ((size_t)blockIdx.x * 256 + threadIdx.x) * 8;
  const float* s;
  size_t off;
  if (e < HN)               { s = h;  off = e; }
  else if (e < HN + WN)     { s = wq; off = e - HN; }
  else if (e < HN + 2 * WN) { s = wk; off = e - HN - WN; }
  else                      { s = wv; off = e - HN - 2 * WN; }
  float4 f0 = *(const float4*)(s + off);
  float4 f1 = *(const float4*)(s + off + 4);
  u32x4 o;
  o[0] = f2bf(f0.x) | ((unsigned int)f2bf(f0.y) << 16);
  o[1] = f2bf(f0.z) | ((unsigned int)f2bf(f0.w) << 16);
  o[2] = f2bf(f1.x) | ((unsigned int)f2bf(f1.y) << 16);
  o[3] = f2bf(f1.z) | ((unsigned int)f2bf(f1.w) << 16);
  *(u32x4*)(out + e) = o;
}

// ---------------------------------------------------------------------------
// MFMA GEMM: C[m,n] = sum_k A[m,k]*B[n,k].  A = hb (16384x256 bf16),
// B = wb + z*WN (512x256 bf16, i.e. B^T k-contiguous). C -> Qb/Kb/Vb bf16.
// 128x128 tile, 4 waves (2x2 of 64x64), BK=32, 16x16x32 MFMA intrinsic
// (compiler handles MFMA hazards), global_load_lds width-16 staging
// (linear LDS: wave-uniform base + lane*16B, verified consistent with the
// per-lane global addresses below).
// ---------------------------------------------------------------------------
__global__ __launch_bounds__(256) void gemm_mfma_kernel(
    const unsigned short* __restrict__ hb,
    const unsigned short* __restrict__ wb,
    unsigned short* __restrict__ Qb, unsigned short* __restrict__ Kb,
    unsigned short* __restrict__ Vb) {
  const unsigned short* B = wb + (size_t)blockIdx.z * WN;
  unsigned short* C = blockIdx.z == 0 ? Qb : (blockIdx.z == 1 ? Kb : Vb);

  __shared__ __align__(16) unsigned short As[128 * 32];
  __shared__ __align__(16) unsigned short Bs[128 * 32];

  const int tid = threadIdx.x;
  const int lane = tid & 63, w = tid >> 6;
  const int row0 = blockIdx.y * 128, col0 = blockIdx.x * 128;
  const int wr = w >> 1, wc = w & 1;

  f32x4 acc[4][4] = {};

  for (int kt = 0; kt < CIN; kt += 32) {
#pragma unroll
    for (int u = 0; u < 2; ++u) {
      int blk = u * 4 + w;                        // 16-row block of the tile
      int r = blk * 16 + (lane >> 2);
      int kc = (lane & 3) * 8;
      __builtin_amdgcn_global_load_lds(
          (const __attribute__((address_space(1))) void*)(hb + (size_t)(row0 + r) * CIN + kt + kc),
          (__attribute__((address_space(3))) void*)(As + blk * 512), 16, 0, 0);
      __builtin_amdgcn_global_load_lds(
          (const __attribute__((address_space(1))) void*)(B + (size_t)(col0 + r) * CIN + kt + kc),
          (__attribute__((address_space(3))) void*)(Bs + blk * 512), 16, 0, 0);
    }
    __syncthreads();   // compiler drains vmcnt before s_barrier

    s16x8 af[4], bfr[4];
#pragma unroll
    for (int mi = 0; mi < 4; ++mi)
      af[mi] = *(const s16x8*)(As + (wr * 64 + mi * 16 + (lane & 15)) * 32 + (lane >> 4) * 8);
#pragma unroll
    for (int ni = 0; ni < 4; ++ni)
      bfr[ni] = *(const s16x8*)(Bs + (wc * 64 + ni * 16 + (lane & 15)) * 32 + (lane >> 4) * 8);
#pragma unroll
    for (int mi = 0; mi < 4; ++mi)
#pragma unroll
      for (int ni = 0; ni < 4; ++ni)
        acc[mi][ni] = __builtin_amdgcn_mfma_f32_16x16x32_bf16(
            af[mi], bfr[ni], acc[mi][ni], 0, 0, 0);
    __syncthreads();
  }

  // C/D layout: col = lane&15, row = (lane>>4)*4 + reg  [m89/m91]
#pragma unroll
  for (int mi = 0; mi < 4; ++mi) {
    int rbase = row0 + wr * 64 + mi * 16 + (lane >> 4) * 4;
#pragma unroll
    for (int ni = 0; ni < 4; ++ni) {
      int c = col0 + wc * 64 + ni * 16 + (lane & 15);
#pragma unroll
      for (int r = 0; r < 4; ++r)
        C[(size_t)(rbase + r) * HD + c] = f2bf(acc[mi][ni][r]);
    }
  }
}

// ---------------------------------------------------------------------------
// RoPE, in-place on bf16 Q and K. One thread per (row-slice rem, axis q):
// owns 32 contiguous bf16 (16 rotation pairs (i, i+16)), so in-place is
// race-free. rem = (b*H+hd)*N + n (torch-faithful flat view); angle =
// pos[b,n,q]*64 * 10000^(-i/16).
// ---------------------------------------------------------------------------
__global__ __launch_bounds__(256) void rope_kernel(
    unsigned short* __restrict__ Qb, unsigned short* __restrict__ Kb,
    const float* __restrict__ pos) {
  const float INVF[16] = {
      1.0f, 0.5623413252f, 0.3162277660f, 0.1778279410f,
      0.1f, 0.05623413252f, 0.03162277660f, 0.01778279410f,
      0.01f, 0.005623413252f, 0.003162277660f, 0.001778279410f,
      0.001f, 0.0005623413252f, 0.0003162277660f, 0.0001778279410f};
  int t = blockIdx.x * 256 + threadIdx.x;     // [0, 2*131072*2)
  unsigned short* M = (t >> 18) ? Kb : Qb;
  int p = t & ((1 << 18) - 1);
  int rem = p >> 1, q = p & 1;
  int n = rem & (NPOS - 1);
  int b = rem >> 15;
  float ps = pos[((size_t)((b << 12) + n)) * 2 + q] * 64.0f;

  unsigned short* base = M + (size_t)rem * DDIM + q * 32;
  u32x4 lo0 = *(u32x4*)(base);        // elems 0..7
  u32x4 lo1 = *(u32x4*)(base + 8);    // elems 8..15
  u32x4 hi0 = *(u32x4*)(base + 16);   // elems 16..23
  u32x4 hi1 = *(u32x4*)(base + 24);   // elems 24..31
  float lo[16], hi[16];
#pragma unroll
  for (int j = 0; j < 4; ++j) {
    lo[2 * j]     = __uint_as_float(lo0[j] << 16);
    lo[2 * j + 1] = __uint_as_float(lo0[j] & 0xffff0000u);
    lo[8 + 2 * j]     = __uint_as_float(lo1[j] << 16);
    lo[8 + 2 * j + 1] = __uint_as_float(lo1[j] & 0xffff0000u);
    hi[2 * j]     = __uint_as_float(hi0[j] << 16);
    hi[2 * j + 1] = __uint_as_float(hi0[j] & 0xffff0000u);
    hi[8 + 2 * j]     = __uint_as_float(hi1[j] << 16);
    hi[8 + 2 * j + 1] = __uint_as_float(hi1[j] & 0xffff0000u);
  }
  unsigned short o[32];
#pragma unroll
  for (int i = 0; i < 16; ++i) {
    float s, c;
    sincosf(ps * INVF[i], &s, &c);
    o[i]      = f2bf(lo[i] * c - hi[i] * s);
    o[i + 16] = f2bf(hi[i] * c + lo[i] * s);
  }
  u32x4 ov;
#pragma unroll
  for (int blkk = 0; blkk < 4; ++blkk) {
#pragma unroll
    for (int j = 0; j < 4; ++j)
      ov[j] = (unsigned int)o[blkk * 8 + 2 * j] |
              ((unsigned int)o[blkk * 8 + 2 * j + 1] << 16);
    *(u32x4*)(base + blkk * 8) = ov;
  }
}

// ---------------------------------------------------------------------------
// Counting sort of edges by dst: histogram -> prefix scan -> scatter.
// ---------------------------------------------------------------------------
__global__ __launch_bounds__(256) void hist_kernel(
    const int* __restrict__ dst, int* __restrict__ count, int E) {
  int t = blockIdx.x * 256 + threadIdx.x;
  if (t < E) atomicAdd(&count[dst[t]], 1);
}

__global__ __launch_bounds__(256) void scan_kernel(
    const int* __restrict__ count, int* __restrict__ offset,
    int* __restrict__ cursor) {
  __shared__ int psum[256];
  __shared__ int pref[256];
  int t = threadIdx.x;
  int base = t * (NODES / 256);
  int s = 0;
  for (int i = 0; i < NODES / 256; ++i) s += count[base + i];
  psum[t] = s;
  __syncthreads();
  if (t == 0) {
    int run = 0;
    for (int i = 0; i < 256; ++i) { pref[i] = run; run += psum[i]; }
  }
  __syncthreads();
  int off = pref[t];
  for (int i = 0; i < NODES / 256; ++i) {
    int c = count[base + i];
    offset[base + i] = off;
    cursor[base + i] = off;
    off += c;
  }
  if (t == 255) offset[NODES] = off;
}

__global__ __launch_bounds__(256) void scatter_kernel(
    const int* __restrict__ src, const int* __restrict__ dst,
    int* __restrict__ cursor, int* __restrict__ srcs, int E) {
  int t = blockIdx.x * 256 + threadIdx.x;
  if (t < E) {
    int p = atomicAdd(&cursor[dst[t]], 1);
    srcs[p] = src[t];
  }
}

// ---------------------------------------------------------------------------
// Node-centric attention (bf16 gathers, fp32 math). One workgroup (4 waves)
// per destination node. lane*8 = this lane's 8 dims of the 512-dim row;
// head hh = lane>>3; dot reduced over the 8-lane head group.
// ---------------------------------------------------------------------------
__global__ __launch_bounds__(256) void node_kernel(
    const unsigned short* __restrict__ Qb, const unsigned short* __restrict__ Kb,
    const unsigned short* __restrict__ Vb,
    const int* __restrict__ srcs, const int* __restrict__ offset,
    float* __restrict__ out) {
  __shared__ float wv[4][HD];
  __shared__ float zb[4][NHEAD];
  const int n = blockIdx.x;
  const int tid = threadIdx.x;
  const int lane = tid & 63, w = tid >> 6;
  const int hh = lane >> 3, g = lane & 7;

  const int beg = offset[n], end = offset[n + 1];

  u32x4 qu = *(const u32x4*)(Qb + (size_t)n * HD + lane * 8);
  float qf[8];
#pragma unroll
  for (int j = 0; j < 4; ++j) {
    qf[2 * j]     = __uint_as_float(qu[j] << 16);
    qf[2 * j + 1] = __uint_as_float(qu[j] & 0xffff0000u);
  }

  float a[8] = {0, 0, 0, 0, 0, 0, 0, 0};
  float zacc = 0.f;

  for (int i = beg + w; i < end; i += 4) {
    int s = srcs[i];
    u32x4 ku = *(const u32x4*)(Kb + (size_t)s * HD + lane * 8);
    float dot = 0.f;
#pragma unroll
    for (int j = 0; j < 4; ++j) {
      dot += __uint_as_float(ku[j] << 16) * qf[2 * j];
      dot += __uint_as_float(ku[j] & 0xffff0000u) * qf[2 * j + 1];
    }
    dot += __shfl_xor(dot, 1);
    dot += __shfl_xor(dot, 2);
    dot += __shfl_xor(dot, 4);
    float sc = expf(fminf(fmaxf(dot * 0.125f, -5.0f), 5.0f));
    u32x4 vu = *(const u32x4*)(Vb + (size_t)s * HD + lane * 8);
#pragma unroll
    for (int j = 0; j < 4; ++j) {
      a[2 * j]     += __uint_as_float(vu[j] << 16) * sc;
      a[2 * j + 1] += __uint_as_float(vu[j] & 0xffff0000u) * sc;
    }
    zacc += sc;   // all 8 lanes of a head group hold the same sc
  }

  *(float4*)&wv[w][lane * 8]     = make_float4(a[0], a[1], a[2], a[3]);
  *(float4*)&wv[w][lane * 8 + 4] = make_float4(a[4], a[5], a[6], a[7]);
  if (g == 0) zb[w][hh] = zacc;
  __syncthreads();

  const int d0 = tid * 2;
  float r0 = wv[0][d0] + wv[1][d0] + wv[2][d0] + wv[3][d0];
  float r1 = wv[0][d0 + 1] + wv[1][d0 + 1] + wv[2][d0 + 1] + wv[3][d0 + 1];
  const int head = d0 >> 6;
  float zz = zb[0][head] + zb[1][head] + zb[2][head] + zb[3][head];
  float inv = 1.0f / zz;
  *(float2*)&out[(size_t)n * HD + d0] = make_float2(r0 * inv, r1 * inv);
}

extern "C" void kernel_launch(void* const* d_in, const int* in_sizes, int n_in,
                              void* d_out, int out_size, void* d_ws,
                              size_t ws_size, hipStream_t stream) {
  const float* h   = (const float*)d_in[0];
  const float* pos = (const float*)d_in[1];
  const float* Wq  = (const float*)d_in[2];
  const float* Wk  = (const float*)d_in[3];
  const float* Wv  = (const float*)d_in[4];
  const int* src   = (const int*)d_in[5];
  const int* dst   = (const int*)d_in[6];
  const int E = in_sizes[5];

  // ws layout (ushorts first, then ints)
  unsigned short* hb  = (unsigned short*)d_ws;          // HN
  unsigned short* wb  = hb + HN;                        // 3*WN
  unsigned short* Qb  = wb + 3 * WN;                    // NODES*HD
  unsigned short* Kb  = Qb + (size_t)NODES * HD;
  unsigned short* Vb  = Kb + (size_t)NODES * HD;
  int* count  = (int*)(Vb + (size_t)NODES * HD);        // NODES
  int* offset = count + NODES;                          // NODES+1
  int* cursor = offset + NODES + 1;                     // NODES
  int* srcs   = cursor + NODES;                         // E
  float* out = (float*)d_out;

  hipMemsetAsync(count, 0, NODES * sizeof(int), stream);

  conv_kernel<<<(HN + 3 * WN) / 8 / 256, 256, 0, stream>>>(h, Wq, Wk, Wv, hb);

  gemm_mfma_kernel<<<dim3(HD / 128, NODES / 128, 3), 256, 0, stream>>>(
      hb, wb, Qb, Kb, Vb);

  rope_kernel<<<(2 * 131072 * 2) / 256, 256, 0, stream>>>(Qb, Kb, pos);

  hist_kernel<<<(E + 255) / 256, 256, 0, stream>>>(dst, count, E);
  scan_kernel<<<1, 256, 0, stream>>>(count, offset, cursor);
  scatter_kernel<<<(E + 255) / 256, 256, 0, stream>>>(src, dst, cursor, srcs, E);

  node_kernel<<<NODES, 256, 0, stream>>>(Qb, Kb, Vb, srcs, offset, out);
}

// Round 8
// 320.380 us; speedup vs baseline: 23.4947x; 1.0051x over previous
//
#include <hip/hip_runtime.h>
#include <math.h>

// Problem constants (fixed by reference setup_inputs)
#define NODES 16384   // bs*N
#define CIN   256     // C (= GEMM K)
#define HD    512     // H*D (= GEMM N)
#define NPOS  4096    // N
#define NHEAD 8       // H
#define DDIM  64      // D
#define HN    (NODES * CIN)   // h elements = 4194304
#define WN    (HD * CIN)      // one W = 131072

typedef float f32x4 __attribute__((ext_vector_type(4)));
typedef unsigned int u32x4 __attribute__((ext_vector_type(4)));
typedef short s16x8 __attribute__((ext_vector_type(8)));   // 8 bf16 = 4 VGPRs

__device__ inline unsigned short f2bf(float f) {   // RNE f32 -> bf16 bits
  unsigned int u = __float_as_uint(f);
  u += 0x7fffu + ((u >> 16) & 1u);
  return (unsigned short)(u >> 16);
}

// ---------------------------------------------------------------------------
// Convert h, Wq, Wk, Wv (fp32) -> bf16, packed contiguously in ws.
// One thread per 8 elements.
// ---------------------------------------------------------------------------
__global__ __launch_bounds__(256) void conv_kernel(
    const float* __restrict__ h, const float* __restrict__ wq,
    const float* __restrict__ wk, const float* __restrict__ wv,
    unsigned short* __restrict__ out) {
  size_t e = ((size_t)blockIdx.x * 256 + threadIdx.x) * 8;
  const float* s;
  size_t off;
  if (e < HN)               { s = h;  off = e; }
  else if (e < HN + WN)     { s = wq; off = e - HN; }
  else if (e < HN + 2 * WN) { s = wk; off = e - HN - WN; }
  else                      { s = wv; off = e - HN - 2 * WN; }
  float4 f0 = *(const float4*)(s + off);
  float4 f1 = *(const float4*)(s + off + 4);
  u32x4 o;
  o[0] = f2bf(f0.x) | ((unsigned int)f2bf(f0.y) << 16);
  o[1] = f2bf(f0.z) | ((unsigned int)f2bf(f0.w) << 16);
  o[2] = f2bf(f1.x) | ((unsigned int)f2bf(f1.y) << 16);
  o[3] = f2bf(f1.z) | ((unsigned int)f2bf(f1.w) << 16);
  *(u32x4*)(out + e) = o;
}

// ---------------------------------------------------------------------------
// MFMA GEMM: C[m,n] = sum_k A[m,k]*B[n,k].  A = hb (16384x256 bf16),
// B = wb + z*WN (512x256 bf16, i.e. B^T k-contiguous). C -> Qb/Kb/Vb bf16.
// 128x128 tile, 4 waves (2x2 of 64x64), BK=32, 16x16x32 MFMA intrinsic.
// T3-minimum 2-phase pipeline: double-buffered LDS (32 KB total; BK=64
// dbuf would be 64 KB -> occupancy cliff per m132), STAGE(next) issued
// BEFORE ds_read+MFMA of current, one vmcnt(0)+barrier per K-step
// (__syncthreads emits the drain).
// ---------------------------------------------------------------------------
__global__ __launch_bounds__(256) void gemm_mfma_kernel(
    const unsigned short* __restrict__ hb,
    const unsigned short* __restrict__ wb,
    unsigned short* __restrict__ Qb, unsigned short* __restrict__ Kb,
    unsigned short* __restrict__ Vb) {
  const unsigned short* B = wb + (size_t)blockIdx.z * WN;
  unsigned short* C = blockIdx.z == 0 ? Qb : (blockIdx.z == 1 ? Kb : Vb);

  __shared__ __align__(16) unsigned short As[2][128 * 32];
  __shared__ __align__(16) unsigned short Bs[2][128 * 32];

  const int tid = threadIdx.x;
  const int lane = tid & 63, w = tid >> 6;
  const int row0 = blockIdx.y * 128, col0 = blockIdx.x * 128;
  const int wr = w >> 1, wc = w & 1;

  // lane -> (row, k) of the staged 16B chunks; LDS dest is wave-uniform
  // base + lane*16B which matches (lane>>2)*32 + (lane&3)*8 elems.
  const int r_l = lane >> 2;
  const int kc = (lane & 3) * 8;

  f32x4 acc[4][4] = {};

#define STAGE(bufi, kt)                                                        \
  {                                                                            \
    _Pragma("unroll") for (int u = 0; u < 2; ++u) {                            \
      int blk = u * 4 + w;                                                     \
      int r = blk * 16 + r_l;                                                  \
      __builtin_amdgcn_global_load_lds(                                        \
          (const __attribute__((address_space(1))) void*)(hb +                 \
              (size_t)(row0 + r) * CIN + (kt) + kc),                           \
          (__attribute__((address_space(3))) void*)(&As[bufi][blk * 512]),     \
          16, 0, 0);                                                           \
      __builtin_amdgcn_global_load_lds(                                        \
          (const __attribute__((address_space(1))) void*)(B +                  \
              (size_t)(col0 + r) * CIN + (kt) + kc),                           \
          (__attribute__((address_space(3))) void*)(&Bs[bufi][blk * 512]),     \
          16, 0, 0);                                                           \
    }                                                                          \
  }

  STAGE(0, 0);
  __syncthreads();   // vmcnt(0) drain + barrier: buf 0 ready

  int cur = 0;
  for (int t = 0; t < 8; ++t) {
    if (t < 7) STAGE(cur ^ 1, (t + 1) * 32);   // prefetch overlaps compute

    s16x8 af[4], bfr[4];
#pragma unroll
    for (int mi = 0; mi < 4; ++mi)
      af[mi] = *(const s16x8*)(&As[cur][(wr * 64 + mi * 16 + (lane & 15)) * 32 + (lane >> 4) * 8]);
#pragma unroll
    for (int ni = 0; ni < 4; ++ni)
      bfr[ni] = *(const s16x8*)(&Bs[cur][(wc * 64 + ni * 16 + (lane & 15)) * 32 + (lane >> 4) * 8]);
#pragma unroll
    for (int mi = 0; mi < 4; ++mi)
#pragma unroll
      for (int ni = 0; ni < 4; ++ni)
        acc[mi][ni] = __builtin_amdgcn_mfma_f32_16x16x32_bf16(
            af[mi], bfr[ni], acc[mi][ni], 0, 0, 0);

    __syncthreads();   // drains stage vmcnt; next buf ready for all waves
    cur ^= 1;
  }
#undef STAGE

  // C/D layout: col = lane&15, row = (lane>>4)*4 + reg  [m89/m91]
#pragma unroll
  for (int mi = 0; mi < 4; ++mi) {
    int rbase = row0 + wr * 64 + mi * 16 + (lane >> 4) * 4;
#pragma unroll
    for (int ni = 0; ni < 4; ++ni) {
      int c = col0 + wc * 64 + ni * 16 + (lane & 15);
#pragma unroll
      for (int r = 0; r < 4; ++r)
        C[(size_t)(rbase + r) * HD + c] = f2bf(acc[mi][ni][r]);
    }
  }
}

// ---------------------------------------------------------------------------
// RoPE, in-place on bf16 Q and K. One thread per (row-slice rem, axis q):
// owns 32 contiguous bf16 (16 rotation pairs (i, i+16)), so in-place is
// race-free. rem = (b*H+hd)*N + n (torch-faithful flat view); angle =
// pos[b,n,q]*64 * 10000^(-i/16).
// ---------------------------------------------------------------------------
__global__ __launch_bounds__(256) void rope_kernel(
    unsigned short* __restrict__ Qb, unsigned short* __restrict__ Kb,
    const float* __restrict__ pos) {
  const float INVF[16] = {
      1.0f, 0.5623413252f, 0.3162277660f, 0.1778279410f,
      0.1f, 0.05623413252f, 0.03162277660f, 0.01778279410f,
      0.01f, 0.005623413252f, 0.003162277660f, 0.001778279410f,
      0.001f, 0.0005623413252f, 0.0003162277660f, 0.0001778279410f};
  int t = blockIdx.x * 256 + threadIdx.x;     // [0, 2*131072*2)
  unsigned short* M = (t >> 18) ? Kb : Qb;
  int p = t & ((1 << 18) - 1);
  int rem = p >> 1, q = p & 1;
  int n = rem & (NPOS - 1);
  int b = rem >> 15;
  float ps = pos[((size_t)((b << 12) + n)) * 2 + q] * 64.0f;

  unsigned short* base = M + (size_t)rem * DDIM + q * 32;
  u32x4 lo0 = *(u32x4*)(base);        // elems 0..7
  u32x4 lo1 = *(u32x4*)(base + 8);    // elems 8..15
  u32x4 hi0 = *(u32x4*)(base + 16);   // elems 16..23
  u32x4 hi1 = *(u32x4*)(base + 24);   // elems 24..31
  float lo[16], hi[16];
#pragma unroll
  for (int j = 0; j < 4; ++j) {
    lo[2 * j]     = __uint_as_float(lo0[j] << 16);
    lo[2 * j + 1] = __uint_as_float(lo0[j] & 0xffff0000u);
    lo[8 + 2 * j]     = __uint_as_float(lo1[j] << 16);
    lo[8 + 2 * j + 1] = __uint_as_float(lo1[j] & 0xffff0000u);
    hi[2 * j]     = __uint_as_float(hi0[j] << 16);
    hi[2 * j + 1] = __uint_as_float(hi0[j] & 0xffff0000u);
    hi[8 + 2 * j]     = __uint_as_float(hi1[j] << 16);
    hi[8 + 2 * j + 1] = __uint_as_float(hi1[j] & 0xffff0000u);
  }
  unsigned short o[32];
#pragma unroll
  for (int i = 0; i < 16; ++i) {
    float s, c;
    sincosf(ps * INVF[i], &s, &c);
    o[i]      = f2bf(lo[i] * c - hi[i] * s);
    o[i + 16] = f2bf(hi[i] * c + lo[i] * s);
  }
  u32x4 ov;
#pragma unroll
  for (int blkk = 0; blkk < 4; ++blkk) {
#pragma unroll
    for (int j = 0; j < 4; ++j)
      ov[j] = (unsigned int)o[blkk * 8 + 2 * j] |
              ((unsigned int)o[blkk * 8 + 2 * j + 1] << 16);
    *(u32x4*)(base + blkk * 8) = ov;
  }
}

// ---------------------------------------------------------------------------
// Counting sort of edges by dst: histogram -> prefix scan -> scatter.
// ---------------------------------------------------------------------------
__global__ __launch_bounds__(256) void hist_kernel(
    const int* __restrict__ dst, int* __restrict__ count, int E) {
  int t = blockIdx.x * 256 + threadIdx.x;
  if (t < E) atomicAdd(&count[dst[t]], 1);
}

__global__ __launch_bounds__(256) void scan_kernel(
    const int* __restrict__ count, int* __restrict__ offset,
    int* __restrict__ cursor) {
  __shared__ int psum[256];
  __shared__ int pref[256];
  int t = threadIdx.x;
  int base = t * (NODES / 256);
  int s = 0;
  for (int i = 0; i < NODES / 256; ++i) s += count[base + i];
  psum[t] = s;
  __syncthreads();
  if (t == 0) {
    int run = 0;
    for (int i = 0; i < 256; ++i) { pref[i] = run; run += psum[i]; }
  }
  __syncthreads();
  int off = pref[t];
  for (int i = 0; i < NODES / 256; ++i) {
    int c = count[base + i];
    offset[base + i] = off;
    cursor[base + i] = off;
    off += c;
  }
  if (t == 255) offset[NODES] = off;
}

__global__ __launch_bounds__(256) void scatter_kernel(
    const int* __restrict__ src, const int* __restrict__ dst,
    int* __restrict__ cursor, int* __restrict__ srcs, int E) {
  int t = blockIdx.x * 256 + threadIdx.x;
  if (t < E) {
    int p = atomicAdd(&cursor[dst[t]], 1);
    srcs[p] = src[t];
  }
}

// ---------------------------------------------------------------------------
// Node-centric attention (bf16 gathers, fp32 math). One workgroup (4 waves)
// per destination node. lane*8 = this lane's 8 dims of the 512-dim row;
// head hh = lane>>3; dot reduced over the 8-lane head group.
// 2-way unrolled edge loop: K0/K1/V0/V1 issued before first use -> 2x
// outstanding gathers per wave (latency-bound fix).
// ---------------------------------------------------------------------------
__global__ __launch_bounds__(256) void node_kernel(
    const unsigned short* __restrict__ Qb, const unsigned short* __restrict__ Kb,
    const unsigned short* __restrict__ Vb,
    const int* __restrict__ srcs, const int* __restrict__ offset,
    float* __restrict__ out) {
  __shared__ float wv[4][HD];
  __shared__ float zb[4][NHEAD];
  const int n = blockIdx.x;
  const int tid = threadIdx.x;
  const int lane = tid & 63, w = tid >> 6;
  const int hh = lane >> 3, g = lane & 7;

  const int beg = offset[n], end = offset[n + 1];

  u32x4 qu = *(const u32x4*)(Qb + (size_t)n * HD + lane * 8);
  float qf[8];
#pragma unroll
  for (int j = 0; j < 4; ++j) {
    qf[2 * j]     = __uint_as_float(qu[j] << 16);
    qf[2 * j + 1] = __uint_as_float(qu[j] & 0xffff0000u);
  }

  float a[8] = {0, 0, 0, 0, 0, 0, 0, 0};
  float zacc = 0.f;

  int i = beg + w;
  for (; i + 4 < end; i += 8) {
    int s0 = srcs[i];
    int s1 = srcs[i + 4];
    u32x4 ku0 = *(const u32x4*)(Kb + (size_t)s0 * HD + lane * 8);
    u32x4 ku1 = *(const u32x4*)(Kb + (size_t)s1 * HD + lane * 8);
    u32x4 vu0 = *(const u32x4*)(Vb + (size_t)s0 * HD + lane * 8);
    u32x4 vu1 = *(const u32x4*)(Vb + (size_t)s1 * HD + lane * 8);
    float dot0 = 0.f, dot1 = 0.f;
#pragma unroll
    for (int j = 0; j < 4; ++j) {
      dot0 += __uint_as_float(ku0[j] << 16) * qf[2 * j];
      dot0 += __uint_as_float(ku0[j] & 0xffff0000u) * qf[2 * j + 1];
      dot1 += __uint_as_float(ku1[j] << 16) * qf[2 * j];
      dot1 += __uint_as_float(ku1[j] & 0xffff0000u) * qf[2 * j + 1];
    }
    dot0 += __shfl_xor(dot0, 1);
    dot1 += __shfl_xor(dot1, 1);
    dot0 += __shfl_xor(dot0, 2);
    dot1 += __shfl_xor(dot1, 2);
    dot0 += __shfl_xor(dot0, 4);
    dot1 += __shfl_xor(dot1, 4);
    float sc0 = expf(fminf(fmaxf(dot0 * 0.125f, -5.0f), 5.0f));
    float sc1 = expf(fminf(fmaxf(dot1 * 0.125f, -5.0f), 5.0f));
#pragma unroll
    for (int j = 0; j < 4; ++j) {
      a[2 * j]     += __uint_as_float(vu0[j] << 16) * sc0 +
                      __uint_as_float(vu1[j] << 16) * sc1;
      a[2 * j + 1] += __uint_as_float(vu0[j] & 0xffff0000u) * sc0 +
                      __uint_as_float(vu1[j] & 0xffff0000u) * sc1;
    }
    zacc += sc0 + sc1;
  }
  for (; i < end; i += 4) {
    int s = srcs[i];
    u32x4 ku = *(const u32x4*)(Kb + (size_t)s * HD + lane * 8);
    u32x4 vu = *(const u32x4*)(Vb + (size_t)s * HD + lane * 8);
    float dot = 0.f;
#pragma unroll
    for (int j = 0; j < 4; ++j) {
      dot += __uint_as_float(ku[j] << 16) * qf[2 * j];
      dot += __uint_as_float(ku[j] & 0xffff0000u) * qf[2 * j + 1];
    }
    dot += __shfl_xor(dot, 1);
    dot += __shfl_xor(dot, 2);
    dot += __shfl_xor(dot, 4);
    float sc = expf(fminf(fmaxf(dot * 0.125f, -5.0f), 5.0f));
#pragma unroll
    for (int j = 0; j < 4; ++j) {
      a[2 * j]     += __uint_as_float(vu[j] << 16) * sc;
      a[2 * j + 1] += __uint_as_float(vu[j] & 0xffff0000u) * sc;
    }
    zacc += sc;
  }

  *(float4*)&wv[w][lane * 8]     = make_float4(a[0], a[1], a[2], a[3]);
  *(float4*)&wv[w][lane * 8 + 4] = make_float4(a[4], a[5], a[6], a[7]);
  if (g == 0) zb[w][hh] = zacc;
  __syncthreads();

  const int d0 = tid * 2;
  float r0 = wv[0][d0] + wv[1][d0] + wv[2][d0] + wv[3][d0];
  float r1 = wv[0][d0 + 1] + wv[1][d0 + 1] + wv[2][d0 + 1] + wv[3][d0 + 1];
  const int head = d0 >> 6;
  float zz = zb[0][head] + zb[1][head] + zb[2][head] + zb[3][head];
  float inv = 1.0f / zz;
  *(float2*)&out[(size_t)n * HD + d0] = make_float2(r0 * inv, r1 * inv);
}

extern "C" void kernel_launch(void* const* d_in, const int* in_sizes, int n_in,
                              void* d_out, int out_size, void* d_ws,
                              size_t ws_size, hipStream_t stream) {
  const float* h   = (const float*)d_in[0];
  const float* pos = (const float*)d_in[1];
  const float* Wq  = (const float*)d_in[2];
  const float* Wk  = (const float*)d_in[3];
  const float* Wv  = (const float*)d_in[4];
  const int* src   = (const int*)d_in[5];
  const int* dst   = (const int*)d_in[6];
  const int E = in_sizes[5];

  // ws layout (ushorts first, then ints)
  unsigned short* hb  = (unsigned short*)d_ws;          // HN
  unsigned short* wb  = hb + HN;                        // 3*WN
  unsigned short* Qb  = wb + 3 * WN;                    // NODES*HD
  unsigned short* Kb  = Qb + (size_t)NODES * HD;
  unsigned short* Vb  = Kb + (size_t)NODES * HD;
  int* count  = (int*)(Vb + (size_t)NODES * HD);        // NODES
  int* offset = count + NODES;                          // NODES+1
  int* cursor = offset + NODES + 1;                     // NODES
  int* srcs   = cursor + NODES;                         // E
  float* out = (float*)d_out;

  hipMemsetAsync(count, 0, NODES * sizeof(int), stream);

  conv_kernel<<<(HN + 3 * WN) / 8 / 256, 256, 0, stream>>>(h, Wq, Wk, Wv, hb);

  gemm_mfma_kernel<<<dim3(HD / 128, NODES / 128, 3), 256, 0, stream>>>(
      hb, wb, Qb, Kb, Vb);

  rope_kernel<<<(2 * 131072 * 2) / 256, 256, 0, stream>>>(Qb, Kb, pos);

  hist_kernel<<<(E + 255) / 256, 256, 0, stream>>>(dst, count, E);
  scan_kernel<<<1, 256, 0, stream>>>(count, offset, cursor);
  scatter_kernel<<<(E + 255) / 256, 256, 0, stream>>>(src, dst, cursor, srcs, E);

  node_kernel<<<NODES, 256, 0, stream>>>(Qb, Kb, Vb, srcs, offset, out);
}

// Round 10
// 307.990 us; speedup vs baseline: 24.4399x; 1.0402x over previous
//
#include <hip/hip_runtime.h>
#include <math.h>

// Problem constants (fixed by reference setup_inputs)
#define NODES 16384   // bs*N
#define CIN   256     // C (= GEMM K)
#define HD    512     // H*D (= GEMM N)
#define NPOS  4096    // N
#define NHEAD 8       // H
#define DDIM  64      // D
#define HN    (NODES * CIN)   // h elements = 4194304
#define WN    (HD * CIN)      // one W = 131072

typedef float f32x4 __attribute__((ext_vector_type(4)));
typedef unsigned int u32x4 __attribute__((ext_vector_type(4)));
typedef short s16x8 __attribute__((ext_vector_type(8)));   // 8 bf16 = 4 VGPRs

__device__ inline unsigned short f2bf(float f) {   // RNE f32 -> bf16 bits
  unsigned int u = __float_as_uint(f);
  u += 0x7fffu + ((u >> 16) & 1u);
  return (unsigned short)(u >> 16);
}

// ---------------------------------------------------------------------------
// Convert h, Wq, Wk, Wv (fp32) -> bf16 packed in ws; threads t < E also do
// the dst histogram (fused hist pass; count must be memset to 0 upstream).
// ---------------------------------------------------------------------------
__global__ __launch_bounds__(256) void conv_hist_kernel(
    const float* __restrict__ h, const float* __restrict__ wq,
    const float* __restrict__ wk, const float* __restrict__ wv,
    unsigned short* __restrict__ out,
    const int* __restrict__ dst, int* __restrict__ count, int E) {
  int t = blockIdx.x * 256 + threadIdx.x;
  if (t < E) atomicAdd(&count[dst[t]], 1);

  size_t e = (size_t)t * 8;
  const float* s;
  size_t off;
  if (e < HN)               { s = h;  off = e; }
  else if (e < HN + WN)     { s = wq; off = e - HN; }
  else if (e < HN + 2 * WN) { s = wk; off = e - HN - WN; }
  else                      { s = wv; off = e - HN - 2 * WN; }
  float4 f0 = *(const float4*)(s + off);
  float4 f1 = *(const float4*)(s + off + 4);
  u32x4 o;
  o[0] = f2bf(f0.x) | ((unsigned int)f2bf(f0.y) << 16);
  o[1] = f2bf(f0.z) | ((unsigned int)f2bf(f0.w) << 16);
  o[2] = f2bf(f1.x) | ((unsigned int)f2bf(f1.y) << 16);
  o[3] = f2bf(f1.z) | ((unsigned int)f2bf(f1.w) << 16);
  *(u32x4*)(out + e) = o;
}

// ---------------------------------------------------------------------------
// MFMA GEMM with fused RoPE epilogue.  C[m,n] = sum_k A[m,k]*B[n,k].
// A = hb (16384x256 bf16), B = wb + z*WN (512x256 bf16). C -> Qb/Kb/Vb bf16.
// 128x128 tile, 4 waves (2x2 of 64x64), BK=32, 2-phase dbuf pipeline.
//
// RoPE fusion (z<2 only): the wave's 64-col sub-tile covers exactly one
// head (head = bx*2 + wc). Within it, ni=0/1 are the x-axis rotation pair
// (dims i, i+16; i = lane&15) and ni=2/3 the y-axis pair. Torch-faithful
// view: flat elem (row*512+col) -> per-batch chunk rem = (row&4095)*8+head,
// position n = rem & 4095, b = row>>12. angle = pos[b,n,axis]*64*invf,
// invf = 10000^(-(lane&15)/16) computed via exp2f (no lane-indexed table).
// ---------------------------------------------------------------------------
__global__ __launch_bounds__(256) void gemm_mfma_kernel(
    const unsigned short* __restrict__ hb,
    const unsigned short* __restrict__ wb,
    const float* __restrict__ pos,
    unsigned short* __restrict__ Qb, unsigned short* __restrict__ Kb,
    unsigned short* __restrict__ Vb) {
  const int z = blockIdx.z;
  const unsigned short* B = wb + (size_t)z * WN;
  unsigned short* C = z == 0 ? Qb : (z == 1 ? Kb : Vb);

  __shared__ __align__(16) unsigned short As[2][128 * 32];
  __shared__ __align__(16) unsigned short Bs[2][128 * 32];

  const int tid = threadIdx.x;
  const int lane = tid & 63, w = tid >> 6;
  const int row0 = blockIdx.y * 128, col0 = blockIdx.x * 128;
  const int wr = w >> 1, wc = w & 1;

  const int r_l = lane >> 2;
  const int kc = (lane & 3) * 8;

  f32x4 acc[4][4] = {};

#define STAGE(bufi, kt)                                                        \
  {                                                                            \
    _Pragma("unroll") for (int u = 0; u < 2; ++u) {                            \
      int blk = u * 4 + w;                                                     \
      int r = blk * 16 + r_l;                                                  \
      __builtin_amdgcn_global_load_lds(                                        \
          (const __attribute__((address_space(1))) void*)(hb +                 \
              (size_t)(row0 + r) * CIN + (kt) + kc),                           \
          (__attribute__((address_space(3))) void*)(&As[bufi][blk * 512]),     \
          16, 0, 0);                                                           \
      __builtin_amdgcn_global_load_lds(                                        \
          (const __attribute__((address_space(1))) void*)(B +                  \
              (size_t)(col0 + r) * CIN + (kt) + kc),                           \
          (__attribute__((address_space(3))) void*)(&Bs[bufi][blk * 512]),     \
          16, 0, 0);                                                           \
    }                                                                          \
  }

  STAGE(0, 0);
  __syncthreads();

  int cur = 0;
  for (int t = 0; t < 8; ++t) {
    if (t < 7) STAGE(cur ^ 1, (t + 1) * 32);   // prefetch overlaps compute

    s16x8 af[4], bfr[4];
#pragma unroll
    for (int mi = 0; mi < 4; ++mi)
      af[mi] = *(const s16x8*)(&As[cur][(wr * 64 + mi * 16 + (lane & 15)) * 32 + (lane >> 4) * 8]);
#pragma unroll
    for (int ni = 0; ni < 4; ++ni)
      bfr[ni] = *(const s16x8*)(&Bs[cur][(wc * 64 + ni * 16 + (lane & 15)) * 32 + (lane >> 4) * 8]);
#pragma unroll
    for (int mi = 0; mi < 4; ++mi)
#pragma unroll
      for (int ni = 0; ni < 4; ++ni)
        acc[mi][ni] = __builtin_amdgcn_mfma_f32_16x16x32_bf16(
            af[mi], bfr[ni], acc[mi][ni], 0, 0, 0);

    __syncthreads();
    cur ^= 1;
  }
#undef STAGE

  // Epilogue. C/D layout: col = lane&15, row = (lane>>4)*4 + reg  [m89/m91]
  const int head = blockIdx.x * 2 + wc;            // col0/64 + wc
  const int cb = col0 + wc * 64 + (lane & 15);     // col for ni=0
  // invf = 10000^(-(lane&15)/16) = exp2(-(lane&15) * log2(10000)/16)
  const float invf = exp2f(-(float)(lane & 15) * 0.83048202372184f);

#pragma unroll
  for (int mi = 0; mi < 4; ++mi) {
#pragma unroll
    for (int r = 0; r < 4; ++r) {
      int row = row0 + wr * 64 + mi * 16 + (lane >> 4) * 4 + r;
      float v0 = acc[mi][0][r], v1 = acc[mi][1][r];
      float v2 = acc[mi][2][r], v3 = acc[mi][3][r];
      if (z < 2) {   // wave-uniform branch: RoPE for Q and K
        int b = row >> 12;
        int rem = ((row & 4095) << 3) + head;      // per-batch 64-chunk index
        int n = rem & (NPOS - 1);
        const float* pp = pos + ((size_t)((b << 12) + n)) * 2;
        float a0 = pp[0] * 64.0f * invf;
        float a1 = pp[1] * 64.0f * invf;
        float s0, c0, s1, c1;
        sincosf(a0, &s0, &c0);
        sincosf(a1, &s1, &c1);
        float nx0 = v0 * c0 - v1 * s0;
        float nx1 = v1 * c0 + v0 * s0;
        float ny0 = v2 * c1 - v3 * s1;
        float ny1 = v3 * c1 + v2 * s1;
        v0 = nx0; v1 = nx1; v2 = ny0; v3 = ny1;
      }
      unsigned short* cp = C + (size_t)row * HD + cb;
      cp[0]  = f2bf(v0);
      cp[16] = f2bf(v1);
      cp[32] = f2bf(v2);
      cp[48] = f2bf(v3);
    }
  }
}

// ---------------------------------------------------------------------------
// Prefix scan of per-dst counts (single block).
// ---------------------------------------------------------------------------
__global__ __launch_bounds__(256) void scan_kernel(
    const int* __restrict__ count, int* __restrict__ offset,
    int* __restrict__ cursor) {
  __shared__ int psum[256];
  __shared__ int pref[256];
  int t = threadIdx.x;
  int base = t * (NODES / 256);
  int s = 0;
  for (int i = 0; i < NODES / 256; ++i) s += count[base + i];
  psum[t] = s;
  __syncthreads();
  if (t == 0) {
    int run = 0;
    for (int i = 0; i < 256; ++i) { pref[i] = run; run += psum[i]; }
  }
  __syncthreads();
  int off = pref[t];
  for (int i = 0; i < NODES / 256; ++i) {
    int c = count[base + i];
    offset[base + i] = off;
    cursor[base + i] = off;
    off += c;
  }
  if (t == 255) offset[NODES] = off;
}

__global__ __launch_bounds__(256) void scatter_kernel(
    const int* __restrict__ src, const int* __restrict__ dst,
    int* __restrict__ cursor, int* __restrict__ srcs, int E) {
  int t = blockIdx.x * 256 + threadIdx.x;
  if (t < E) {
    int p = atomicAdd(&cursor[dst[t]], 1);
    srcs[p] = src[t];
  }
}

// ---------------------------------------------------------------------------
// Node-centric attention (bf16 gathers, fp32 math). One workgroup (4 waves)
// per destination node. lane*8 = this lane's 8 dims of the 512-dim row;
// head hh = lane>>3; dot reduced over the 8-lane head group.
// Simple loop (r6 form): r8's 2-way unroll was neutral-negative — the phase
// sits at the ~3.7 TB/s random-line fetch ceiling (r3/r6/r8 all cluster
// there), so more outstanding loads don't help.
// ---------------------------------------------------------------------------
__global__ __launch_bounds__(256) void node_kernel(
    const unsigned short* __restrict__ Qb, const unsigned short* __restrict__ Kb,
    const unsigned short* __restrict__ Vb,
    const int* __restrict__ srcs, const int* __restrict__ offset,
    float* __restrict__ out) {
  __shared__ float wv[4][HD];
  __shared__ float zb[4][NHEAD];
  const int n = blockIdx.x;
  const int tid = threadIdx.x;
  const int lane = tid & 63, w = tid >> 6;
  const int hh = lane >> 3, g = lane & 7;

  const int beg = offset[n], end = offset[n + 1];

  u32x4 qu = *(const u32x4*)(Qb + (size_t)n * HD + lane * 8);
  float qf[8];
#pragma unroll
  for (int j = 0; j < 4; ++j) {
    qf[2 * j]     = __uint_as_float(qu[j] << 16);
    qf[2 * j + 1] = __uint_as_float(qu[j] & 0xffff0000u);
  }

  float a[8] = {0, 0, 0, 0, 0, 0, 0, 0};
  float zacc = 0.f;

  for (int i = beg + w; i < end; i += 4) {
    int s = srcs[i];
    u32x4 ku = *(const u32x4*)(Kb + (size_t)s * HD + lane * 8);
    u32x4 vu = *(const u32x4*)(Vb + (size_t)s * HD + lane * 8);
    float dot = 0.f;
#pragma unroll
    for (int j = 0; j < 4; ++j) {
      dot += __uint_as_float(ku[j] << 16) * qf[2 * j];
      dot += __uint_as_float(ku[j] & 0xffff0000u) * qf[2 * j + 1];
    }
    dot += __shfl_xor(dot, 1);
    dot += __shfl_xor(dot, 2);
    dot += __shfl_xor(dot, 4);
    float sc = expf(fminf(fmaxf(dot * 0.125f, -5.0f), 5.0f));
#pragma unroll
    for (int j = 0; j < 4; ++j) {
      a[2 * j]     += __uint_as_float(vu[j] << 16) * sc;
      a[2 * j + 1] += __uint_as_float(vu[j] & 0xffff0000u) * sc;
    }
    zacc += sc;   // all 8 lanes of a head group hold the same sc
  }

  *(float4*)&wv[w][lane * 8]     = make_float4(a[0], a[1], a[2], a[3]);
  *(float4*)&wv[w][lane * 8 + 4] = make_float4(a[4], a[5], a[6], a[7]);
  if (g == 0) zb[w][hh] = zacc;
  __syncthreads();

  const int d0 = tid * 2;
  float r0 = wv[0][d0] + wv[1][d0] + wv[2][d0] + wv[3][d0];
  float r1 = wv[0][d0 + 1] + wv[1][d0 + 1] + wv[2][d0 + 1] + wv[3][d0 + 1];
  const int head = d0 >> 6;
  float zz = zb[0][head] + zb[1][head] + zb[2][head] + zb[3][head];
  float inv = 1.0f / zz;
  *(float2*)&out[(size_t)n * HD + d0] = make_float2(r0 * inv, r1 * inv);
}

extern "C" void kernel_launch(void* const* d_in, const int* in_sizes, int n_in,
                              void* d_out, int out_size, void* d_ws,
                              size_t ws_size, hipStream_t stream) {
  const float* h   = (const float*)d_in[0];
  const float* pos = (const float*)d_in[1];
  const float* Wq  = (const float*)d_in[2];
  const float* Wk  = (const float*)d_in[3];
  const float* Wv  = (const float*)d_in[4];
  const int* src   = (const int*)d_in[5];
  const int* dst   = (const int*)d_in[6];
  const int E = in_sizes[5];

  // ws layout (ushorts first, then ints)
  unsigned short* hb  = (unsigned short*)d_ws;          // HN
  unsigned short* wb  = hb + HN;                        // 3*WN
  unsigned short* Qb  = wb + 3 * WN;                    // NODES*HD
  unsigned short* Kb  = Qb + (size_t)NODES * HD;
  unsigned short* Vb  = Kb + (size_t)NODES * HD;
  int* count  = (int*)(Vb + (size_t)NODES * HD);        // NODES
  int* offset = count + NODES;                          // NODES+1
  int* cursor = offset + NODES + 1;                     // NODES
  int* srcs   = cursor + NODES;                         // E
  float* out = (float*)d_out;

  hipMemsetAsync(count, 0, NODES * sizeof(int), stream);

  conv_hist_kernel<<<(HN + 3 * WN) / 8 / 256, 256, 0, stream>>>(
      h, Wq, Wk, Wv, hb, dst, count, E);

  scan_kernel<<<1, 256, 0, stream>>>(count, offset, cursor);
  scatter_kernel<<<(E + 255) / 256, 256, 0, stream>>>(src, dst, cursor, srcs, E);

  gemm_mfma_kernel<<<dim3(HD / 128, NODES / 128, 3), 256, 0, stream>>>(
      hb, wb, pos, Qb, Kb, Vb);

  node_kernel<<<NODES, 256, 0, stream>>>(Qb, Kb, Vb, srcs, offset, out);
}

// Round 11
// 284.533 us; speedup vs baseline: 26.4547x; 1.0824x over previous
//
#include <hip/hip_runtime.h>
#include <math.h>

// Problem constants (fixed by reference setup_inputs)
#define NODES 16384   // bs*N
#define CIN   256     // C (= GEMM K)
#define HD    512     // H*D (= GEMM N)
#define NPOS  4096    // N
#define NHEAD 8       // H
#define DDIM  64      // D
#define HN    (NODES * CIN)   // h elements = 4194304
#define WN    (HD * CIN)      // one W = 131072

typedef float f32x4 __attribute__((ext_vector_type(4)));
typedef unsigned int u32x4 __attribute__((ext_vector_type(4)));
typedef short s16x8 __attribute__((ext_vector_type(8)));   // 8 bf16 = 4 VGPRs

__device__ inline unsigned short f2bf(float f) {   // RNE f32 -> bf16 bits
  unsigned int u = __float_as_uint(f);
  u += 0x7fffu + ((u >> 16) & 1u);
  return (unsigned short)(u >> 16);
}

// ---------------------------------------------------------------------------
// Convert h, Wq, Wk, Wv (fp32) -> bf16 packed in ws; threads t < E also do
// the dst histogram AND record this edge's rank within its dst bucket
// (atomicAdd return value) -> placement later needs no atomics.
// ---------------------------------------------------------------------------
__global__ __launch_bounds__(256) void conv_rank_kernel(
    const float* __restrict__ h, const float* __restrict__ wq,
    const float* __restrict__ wk, const float* __restrict__ wv,
    unsigned short* __restrict__ out,
    const int* __restrict__ dst, int* __restrict__ count,
    int* __restrict__ rank, int E) {
  int t = blockIdx.x * 256 + threadIdx.x;
  if (t < E) rank[t] = atomicAdd(&count[dst[t]], 1);

  size_t e = (size_t)t * 8;
  const float* s;
  size_t off;
  if (e < HN)               { s = h;  off = e; }
  else if (e < HN + WN)     { s = wq; off = e - HN; }
  else if (e < HN + 2 * WN) { s = wk; off = e - HN - WN; }
  else                      { s = wv; off = e - HN - 2 * WN; }
  float4 f0 = *(const float4*)(s + off);
  float4 f1 = *(const float4*)(s + off + 4);
  u32x4 o;
  o[0] = f2bf(f0.x) | ((unsigned int)f2bf(f0.y) << 16);
  o[1] = f2bf(f0.z) | ((unsigned int)f2bf(f0.w) << 16);
  o[2] = f2bf(f1.x) | ((unsigned int)f2bf(f1.y) << 16);
  o[3] = f2bf(f1.z) | ((unsigned int)f2bf(f1.w) << 16);
  *(u32x4*)(out + e) = o;
}

// ---------------------------------------------------------------------------
// Prefix scan of per-dst counts (single block, 256 threads, 64 counts each).
// 256 partials scanned by wave 0 via shfl_up tree (no serial 256-loop).
// ---------------------------------------------------------------------------
__global__ __launch_bounds__(256) void scan_kernel(
    const int* __restrict__ count, int* __restrict__ offset) {
  __shared__ int psum[256];
  __shared__ int pref[256];
  int t = threadIdx.x;
  int base = t * (NODES / 256);
  int s = 0;
  for (int i = 0; i < NODES / 256; ++i) s += count[base + i];
  psum[t] = s;
  __syncthreads();
  if (t < 64) {
    int a0 = psum[4 * t], a1 = psum[4 * t + 1];
    int a2 = psum[4 * t + 2], a3 = psum[4 * t + 3];
    int loc = a0 + a1 + a2 + a3;
    int sc = loc;
#pragma unroll
    for (int d = 1; d < 64; d <<= 1) {
      int v = __shfl_up(sc, d);
      if (t >= d) sc += v;
    }
    int excl = sc - loc;
    pref[4 * t]     = excl;
    pref[4 * t + 1] = excl + a0;
    pref[4 * t + 2] = excl + a0 + a1;
    pref[4 * t + 3] = excl + a0 + a1 + a2;
  }
  __syncthreads();
  int off = pref[t];
  for (int i = 0; i < NODES / 256; ++i) {
    offset[base + i] = off;
    off += count[base + i];
  }
  if (t == 255) offset[NODES] = off;
}

// ---------------------------------------------------------------------------
// Atomic-free placement: slot = offset[dst] + rank (rank from conv pass).
// ---------------------------------------------------------------------------
__global__ __launch_bounds__(256) void place_kernel(
    const int* __restrict__ src, const int* __restrict__ dst,
    const int* __restrict__ offset, const int* __restrict__ rank,
    int* __restrict__ srcs, int E) {
  int t = blockIdx.x * 256 + threadIdx.x;
  if (t < E) srcs[offset[dst[t]] + rank[t]] = src[t];
}

// ---------------------------------------------------------------------------
// MFMA GEMM with fused RoPE epilogue.  C[m,n] = sum_k A[m,k]*B[n,k].
// A = hb (16384x256 bf16), B = wb + z*WN (512x256 bf16). C -> Qb/Kb/Vb bf16.
// 128x128 tile, 4 waves (2x2 of 64x64), BK=32, 2-phase dbuf pipeline.
// RoPE fusion (z<2): head = bx*2+wc; ni=0/1 x-axis pair (i, i+16), ni=2/3
// y-axis; rem = (row&4095)*8+head; angle = pos[b,n,axis]*64*invf.
// ---------------------------------------------------------------------------
__global__ __launch_bounds__(256) void gemm_mfma_kernel(
    const unsigned short* __restrict__ hb,
    const unsigned short* __restrict__ wb,
    const float* __restrict__ pos,
    unsigned short* __restrict__ Qb, unsigned short* __restrict__ Kb,
    unsigned short* __restrict__ Vb) {
  const int z = blockIdx.z;
  const unsigned short* B = wb + (size_t)z * WN;
  unsigned short* C = z == 0 ? Qb : (z == 1 ? Kb : Vb);

  __shared__ __align__(16) unsigned short As[2][128 * 32];
  __shared__ __align__(16) unsigned short Bs[2][128 * 32];

  const int tid = threadIdx.x;
  const int lane = tid & 63, w = tid >> 6;
  const int row0 = blockIdx.y * 128, col0 = blockIdx.x * 128;
  const int wr = w >> 1, wc = w & 1;

  const int r_l = lane >> 2;
  const int kc = (lane & 3) * 8;

  f32x4 acc[4][4] = {};

#define STAGE(bufi, kt)                                                        \
  {                                                                            \
    _Pragma("unroll") for (int u = 0; u < 2; ++u) {                            \
      int blk = u * 4 + w;                                                     \
      int r = blk * 16 + r_l;                                                  \
      __builtin_amdgcn_global_load_lds(                                        \
          (const __attribute__((address_space(1))) void*)(hb +                 \
              (size_t)(row0 + r) * CIN + (kt) + kc),                           \
          (__attribute__((address_space(3))) void*)(&As[bufi][blk * 512]),     \
          16, 0, 0);                                                           \
      __builtin_amdgcn_global_load_lds(                                        \
          (const __attribute__((address_space(1))) void*)(B +                  \
              (size_t)(col0 + r) * CIN + (kt) + kc),                           \
          (__attribute__((address_space(3))) void*)(&Bs[bufi][blk * 512]),     \
          16, 0, 0);                                                           \
    }                                                                          \
  }

  STAGE(0, 0);
  __syncthreads();

  int cur = 0;
  for (int t = 0; t < 8; ++t) {
    if (t < 7) STAGE(cur ^ 1, (t + 1) * 32);   // prefetch overlaps compute

    s16x8 af[4], bfr[4];
#pragma unroll
    for (int mi = 0; mi < 4; ++mi)
      af[mi] = *(const s16x8*)(&As[cur][(wr * 64 + mi * 16 + (lane & 15)) * 32 + (lane >> 4) * 8]);
#pragma unroll
    for (int ni = 0; ni < 4; ++ni)
      bfr[ni] = *(const s16x8*)(&Bs[cur][(wc * 64 + ni * 16 + (lane & 15)) * 32 + (lane >> 4) * 8]);
#pragma unroll
    for (int mi = 0; mi < 4; ++mi)
#pragma unroll
      for (int ni = 0; ni < 4; ++ni)
        acc[mi][ni] = __builtin_amdgcn_mfma_f32_16x16x32_bf16(
            af[mi], bfr[ni], acc[mi][ni], 0, 0, 0);

    __syncthreads();
    cur ^= 1;
  }
#undef STAGE

  // Epilogue. C/D layout: col = lane&15, row = (lane>>4)*4 + reg  [m89/m91]
  const int head = blockIdx.x * 2 + wc;            // col0/64 + wc
  const int cb = col0 + wc * 64 + (lane & 15);     // col for ni=0
  // invf = 10000^(-(lane&15)/16) = exp2(-(lane&15) * log2(10000)/16)
  const float invf = exp2f(-(float)(lane & 15) * 0.83048202372184f);

#pragma unroll
  for (int mi = 0; mi < 4; ++mi) {
#pragma unroll
    for (int r = 0; r < 4; ++r) {
      int row = row0 + wr * 64 + mi * 16 + (lane >> 4) * 4 + r;
      float v0 = acc[mi][0][r], v1 = acc[mi][1][r];
      float v2 = acc[mi][2][r], v3 = acc[mi][3][r];
      if (z < 2) {   // wave-uniform branch: RoPE for Q and K
        int b = row >> 12;
        int rem = ((row & 4095) << 3) + head;      // per-batch 64-chunk index
        int n = rem & (NPOS - 1);
        const float* pp = pos + ((size_t)((b << 12) + n)) * 2;
        float a0 = pp[0] * 64.0f * invf;
        float a1 = pp[1] * 64.0f * invf;
        float s0, c0, s1, c1;
        sincosf(a0, &s0, &c0);
        sincosf(a1, &s1, &c1);
        float nx0 = v0 * c0 - v1 * s0;
        float nx1 = v1 * c0 + v0 * s0;
        float ny0 = v2 * c1 - v3 * s1;
        float ny1 = v3 * c1 + v2 * s1;
        v0 = nx0; v1 = nx1; v2 = ny0; v3 = ny1;
      }
      unsigned short* cp = C + (size_t)row * HD + cb;
      cp[0]  = f2bf(v0);
      cp[16] = f2bf(v1);
      cp[32] = f2bf(v2);
      cp[48] = f2bf(v3);
    }
  }
}

// ---------------------------------------------------------------------------
// Node-centric attention (bf16 gathers, fp32 math). One workgroup (4 waves)
// per destination node. lane*8 = this lane's 8 dims of the 512-dim row;
// head hh = lane>>3; dot reduced over the 8-lane head group.
// Simple loop (r8's unroll was neutral-negative: phase pinned at ~3.7 TB/s
// random-line service rate). __expf replaces library expf (clamped domain).
// ---------------------------------------------------------------------------
__global__ __launch_bounds__(256) void node_kernel(
    const unsigned short* __restrict__ Qb, const unsigned short* __restrict__ Kb,
    const unsigned short* __restrict__ Vb,
    const int* __restrict__ srcs, const int* __restrict__ offset,
    float* __restrict__ out) {
  __shared__ float wv[4][HD];
  __shared__ float zb[4][NHEAD];
  const int n = blockIdx.x;
  const int tid = threadIdx.x;
  const int lane = tid & 63, w = tid >> 6;
  const int hh = lane >> 3, g = lane & 7;

  const int beg = offset[n], end = offset[n + 1];

  u32x4 qu = *(const u32x4*)(Qb + (size_t)n * HD + lane * 8);
  float qf[8];
#pragma unroll
  for (int j = 0; j < 4; ++j) {
    qf[2 * j]     = __uint_as_float(qu[j] << 16);
    qf[2 * j + 1] = __uint_as_float(qu[j] & 0xffff0000u);
  }

  float a[8] = {0, 0, 0, 0, 0, 0, 0, 0};
  float zacc = 0.f;

  for (int i = beg + w; i < end; i += 4) {
    int s = srcs[i];
    u32x4 ku = *(const u32x4*)(Kb + (size_t)s * HD + lane * 8);
    u32x4 vu = *(const u32x4*)(Vb + (size_t)s * HD + lane * 8);
    float dot = 0.f;
#pragma unroll
    for (int j = 0; j < 4; ++j) {
      dot += __uint_as_float(ku[j] << 16) * qf[2 * j];
      dot += __uint_as_float(ku[j] & 0xffff0000u) * qf[2 * j + 1];
    }
    dot += __shfl_xor(dot, 1);
    dot += __shfl_xor(dot, 2);
    dot += __shfl_xor(dot, 4);
    float sc = __expf(fminf(fmaxf(dot * 0.125f, -5.0f), 5.0f));
#pragma unroll
    for (int j = 0; j < 4; ++j) {
      a[2 * j]     += __uint_as_float(vu[j] << 16) * sc;
      a[2 * j + 1] += __uint_as_float(vu[j] & 0xffff0000u) * sc;
    }
    zacc += sc;   // all 8 lanes of a head group hold the same sc
  }

  *(float4*)&wv[w][lane * 8]     = make_float4(a[0], a[1], a[2], a[3]);
  *(float4*)&wv[w][lane * 8 + 4] = make_float4(a[4], a[5], a[6], a[7]);
  if (g == 0) zb[w][hh] = zacc;
  __syncthreads();

  const int d0 = tid * 2;
  float r0 = wv[0][d0] + wv[1][d0] + wv[2][d0] + wv[3][d0];
  float r1 = wv[0][d0 + 1] + wv[1][d0 + 1] + wv[2][d0 + 1] + wv[3][d0 + 1];
  const int head = d0 >> 6;
  float zz = zb[0][head] + zb[1][head] + zb[2][head] + zb[3][head];
  float inv = 1.0f / zz;
  *(float2*)&out[(size_t)n * HD + d0] = make_float2(r0 * inv, r1 * inv);
}

extern "C" void kernel_launch(void* const* d_in, const int* in_sizes, int n_in,
                              void* d_out, int out_size, void* d_ws,
                              size_t ws_size, hipStream_t stream) {
  const float* h   = (const float*)d_in[0];
  const float* pos = (const float*)d_in[1];
  const float* Wq  = (const float*)d_in[2];
  const float* Wk  = (const float*)d_in[3];
  const float* Wv  = (const float*)d_in[4];
  const int* src   = (const int*)d_in[5];
  const int* dst   = (const int*)d_in[6];
  const int E = in_sizes[5];

  // ws layout (ushorts first, then ints)
  unsigned short* hb  = (unsigned short*)d_ws;          // HN
  unsigned short* wb  = hb + HN;                        // 3*WN
  unsigned short* Qb  = wb + 3 * WN;                    // NODES*HD
  unsigned short* Kb  = Qb + (size_t)NODES * HD;
  unsigned short* Vb  = Kb + (size_t)NODES * HD;
  int* count  = (int*)(Vb + (size_t)NODES * HD);        // NODES
  int* offset = count + NODES;                          // NODES+1
  int* rank   = offset + NODES + 1;                     // E
  int* srcs   = rank + E;                               // E
  float* out = (float*)d_out;

  hipMemsetAsync(count, 0, NODES * sizeof(int), stream);

  conv_rank_kernel<<<(HN + 3 * WN) / 8 / 256, 256, 0, stream>>>(
      h, Wq, Wk, Wv, hb, dst, count, rank, E);

  scan_kernel<<<1, 256, 0, stream>>>(count, offset);
  place_kernel<<<(E + 255) / 256, 256, 0, stream>>>(
      src, dst, offset, rank, srcs, E);

  gemm_mfma_kernel<<<dim3(HD / 128, NODES / 128, 3), 256, 0, stream>>>(
      hb, wb, pos, Qb, Kb, Vb);

  node_kernel<<<NODES, 256, 0, stream>>>(Qb, Kb, Vb, srcs, offset, out);
}